// Round 2
// baseline (496.146 us; speedup 1.0000x reference)
//
#include <hip/hip_runtime.h>

#define T_SEQ 4096
#define CC    128
#define HH    32
#define ROWS  16               // query rows per attention wave
#define BK    32               // keys per LDS tile
#define SEGS  4                // split-K segments per row-block
#define BPB   (T_SEQ / ROWS)   // 256 row-blocks per batch

// ---------------------------------------------------------------------------
// Projection: k,q,v = x @ W^T.  q pre-scaled by log2(e)/sqrt(H) so attention
// scores live in the log2 domain (exp2 is the native v_exp_f32).
// Block = 256 threads, 8 rows of x. thread = (r = t>>5, h = t&31).
// ---------------------------------------------------------------------------
__global__ __launch_bounds__(256) void proj_kernel(
    const float* __restrict__ x,
    const float* __restrict__ Wk,
    const float* __restrict__ Wq,
    const float* __restrict__ Wv,
    float* __restrict__ qo,
    float* __restrict__ ko,
    float* __restrict__ vo)
{
    __shared__ __align__(16) float xs[8 * CC];
    const int t = threadIdx.x;
    const long rowBase = (long)blockIdx.x * 8;

    ((float4*)xs)[t] = ((const float4*)(x + rowBase * CC))[t];
    __syncthreads();

    const int r = t >> 5;
    const int h = t & 31;
    const float4* xr = (const float4*)(xs + r * CC);
    const float4* wk = (const float4*)(Wk + h * CC);
    const float4* wq = (const float4*)(Wq + h * CC);
    const float4* wv = (const float4*)(Wv + h * CC);

    float ak0 = 0.f, ak1 = 0.f, aq0 = 0.f, aq1 = 0.f, av0 = 0.f, av1 = 0.f;
    #pragma unroll
    for (int c = 0; c < CC / 4; c += 2) {
        const float4 x0 = xr[c];
        const float4 x1 = xr[c + 1];
        {
            const float4 a0 = wk[c], a1 = wk[c + 1];
            ak0 = fmaf(x0.x, a0.x, ak0); ak0 = fmaf(x0.y, a0.y, ak0);
            ak0 = fmaf(x0.z, a0.z, ak0); ak0 = fmaf(x0.w, a0.w, ak0);
            ak1 = fmaf(x1.x, a1.x, ak1); ak1 = fmaf(x1.y, a1.y, ak1);
            ak1 = fmaf(x1.z, a1.z, ak1); ak1 = fmaf(x1.w, a1.w, ak1);
        }
        {
            const float4 a0 = wq[c], a1 = wq[c + 1];
            aq0 = fmaf(x0.x, a0.x, aq0); aq0 = fmaf(x0.y, a0.y, aq0);
            aq0 = fmaf(x0.z, a0.z, aq0); aq0 = fmaf(x0.w, a0.w, aq0);
            aq1 = fmaf(x1.x, a1.x, aq1); aq1 = fmaf(x1.y, a1.y, aq1);
            aq1 = fmaf(x1.z, a1.z, aq1); aq1 = fmaf(x1.w, a1.w, aq1);
        }
        {
            const float4 a0 = wv[c], a1 = wv[c + 1];
            av0 = fmaf(x0.x, a0.x, av0); av0 = fmaf(x0.y, a0.y, av0);
            av0 = fmaf(x0.z, a0.z, av0); av0 = fmaf(x0.w, a0.w, av0);
            av1 = fmaf(x1.x, a1.x, av1); av1 = fmaf(x1.y, a1.y, av1);
            av1 = fmaf(x1.z, a1.z, av1); av1 = fmaf(x1.w, a1.w, av1);
        }
    }

    const long row = rowBase + r;
    // 1/sqrt(32) * log2(e): scores come out in log2 units
    const float qscale = 0.17677669529663687f * 1.4426950408889634f;
    ko[row * HH + h] = ak0 + ak1;
    qo[row * HH + h] = (aq0 + aq1) * qscale;
    vo[row * HH + h] = av0 + av1;
}

// ---------------------------------------------------------------------------
// Split-K flash attention partial. One wave per block.
// Block = 16 query rows x 4 sublanes (8 dims each). Each block owns a
// contiguous chunk of the row-block's key tiles; writes (acc, m, l) partials.
// Partial entry layout per (b, rb, seg): 16 rows x 36 floats
//   [0..31]=unnormalized acc, [32]=m (log2 domain), [33]=l, [34..35]=pad.
// ---------------------------------------------------------------------------
__global__ __launch_bounds__(64, 4) void attn_partial(
    const float* __restrict__ q,
    const float* __restrict__ k,
    const float* __restrict__ v,
    float* __restrict__ part)
{
    __shared__ __align__(16) float ks[BK * HH];
    __shared__ __align__(16) float vs[BK * HH];

    const int tid = threadIdx.x;
    const int nb  = gridDim.x / SEGS;          // B * BPB
    const int bid = blockIdx.x;
    const int seg = bid / nb;
    const int rem = bid - seg * nb;
    const int b   = rem / BPB;
    const int rbi = rem - b * BPB;
    const int rb  = BPB - 1 - rbi;             // heavy row-blocks first
    const int r0  = rb * ROWS;
    const int r   = tid >> 2;
    const int row = r0 + r;
    const int sub = tid & 3;

    const int nTiles = (r0 + ROWS + BK - 1) / BK;
    const int t0 = seg * nTiles / SEGS;
    const int t1 = (seg + 1) * nTiles / SEGS;

    float* pe = part + ((long)(b * BPB + rb) * SEGS + seg) * (16 * 36) + r * 36;

    if (t0 >= t1) {                            // empty segment
        const float4 z = {0.f, 0.f, 0.f, 0.f};
        *(float4*)(pe + sub * 8)     = z;
        *(float4*)(pe + sub * 8 + 4) = z;
        if (sub == 0) { pe[32] = -1e30f; pe[33] = 0.f; }
        return;
    }

    const long batchOff = (long)b * T_SEQ * HH;
    const float* qp = q + batchOff + (long)row * HH + sub * 8;
    const float4 q0 = *(const float4*)qp;
    const float4 q1 = *(const float4*)(qp + 4);

    const float4* kg = (const float4*)(k + batchOff);
    const float4* vg = (const float4*)(v + batchOff);

    float m = -1e30f, l = 0.f;
    float acc[8];
    #pragma unroll
    for (int d = 0; d < 8; ++d) acc[d] = 0.f;

    // stage tile t0 into registers (tile = 256 float4 per K and V)
    long tb = (long)t0 * (BK * HH / 4);
    float4 rk0 = kg[tb + tid],       rk1 = kg[tb + 64 + tid];
    float4 rk2 = kg[tb + 128 + tid], rk3 = kg[tb + 192 + tid];
    float4 rv0 = vg[tb + tid],       rv1 = vg[tb + 64 + tid];
    float4 rv2 = vg[tb + 128 + tid], rv3 = vg[tb + 192 + tid];

    for (int kt = t0; kt < t1; ++kt) {
        // commit staged registers to LDS (single wave: program order suffices)
        ((float4*)ks)[tid]       = rk0; ((float4*)ks)[64 + tid]  = rk1;
        ((float4*)ks)[128 + tid] = rk2; ((float4*)ks)[192 + tid] = rk3;
        ((float4*)vs)[tid]       = rv0; ((float4*)vs)[64 + tid]  = rv1;
        ((float4*)vs)[128 + tid] = rv2; ((float4*)vs)[192 + tid] = rv3;

        // async-stage next tile: HBM/L2 latency hides under pass1+pass2
        if (kt + 1 < t1) {
            const long nb4 = (long)(kt + 1) * (BK * HH / 4);
            rk0 = kg[nb4 + tid];       rk1 = kg[nb4 + 64 + tid];
            rk2 = kg[nb4 + 128 + tid]; rk3 = kg[nb4 + 192 + tid];
            rv0 = vg[nb4 + tid];       rv1 = vg[nb4 + 64 + tid];
            rv2 = vg[nb4 + 128 + tid]; rv3 = vg[nb4 + 192 + tid];
        }

        // ---- pass 1: scores + tile max ----
        float s[BK];
        float tmax = -1e30f;
        const bool full = (kt * BK + BK - 1) <= r0;   // wave-uniform
        if (full) {
            #pragma unroll
            for (int j = 0; j < BK; ++j) {
                const float4 ka  = *(const float4*)(ks + j * HH + sub * 8);
                const float4 kb4 = *(const float4*)(ks + j * HH + sub * 8 + 4);
                float d0 = ka.x * q0.x;
                d0 = fmaf(ka.y, q0.y, d0); d0 = fmaf(ka.z, q0.z, d0); d0 = fmaf(ka.w, q0.w, d0);
                float d1 = kb4.x * q1.x;
                d1 = fmaf(kb4.y, q1.y, d1); d1 = fmaf(kb4.z, q1.z, d1); d1 = fmaf(kb4.w, q1.w, d1);
                float sj = d0 + d1;
                sj += __shfl_xor(sj, 1);
                sj += __shfl_xor(sj, 2);
                tmax = fmaxf(tmax, sj);
                s[j] = sj;
            }
        } else {
            #pragma unroll
            for (int j = 0; j < BK; ++j) {
                const float4 ka  = *(const float4*)(ks + j * HH + sub * 8);
                const float4 kb4 = *(const float4*)(ks + j * HH + sub * 8 + 4);
                float d0 = ka.x * q0.x;
                d0 = fmaf(ka.y, q0.y, d0); d0 = fmaf(ka.z, q0.z, d0); d0 = fmaf(ka.w, q0.w, d0);
                float d1 = kb4.x * q1.x;
                d1 = fmaf(kb4.y, q1.y, d1); d1 = fmaf(kb4.z, q1.z, d1); d1 = fmaf(kb4.w, q1.w, d1);
                float sj = d0 + d1;
                sj += __shfl_xor(sj, 1);
                sj += __shfl_xor(sj, 2);
                if (kt * BK + j > row) sj = -1e30f;   // causal mask
                tmax = fmaxf(tmax, sj);
                s[j] = sj;
            }
        }

        // ---- online-softmax rescale (once per tile, log2 domain) ----
        const float mn   = fmaxf(m, tmax);
        const float corr = exp2f(m - mn);
        l *= corr;
        #pragma unroll
        for (int d = 0; d < 8; ++d) acc[d] *= corr;
        m = mn;

        // ---- pass 2: exp2 + PV accumulate ----
        #pragma unroll
        for (int j = 0; j < BK; ++j) {
            const float p = exp2f(s[j] - m);
            l += p;
            const float4 va  = *(const float4*)(vs + j * HH + sub * 8);
            const float4 vb4 = *(const float4*)(vs + j * HH + sub * 8 + 4);
            acc[0] = fmaf(p, va.x,  acc[0]);
            acc[1] = fmaf(p, va.y,  acc[1]);
            acc[2] = fmaf(p, va.z,  acc[2]);
            acc[3] = fmaf(p, va.w,  acc[3]);
            acc[4] = fmaf(p, vb4.x, acc[4]);
            acc[5] = fmaf(p, vb4.y, acc[5]);
            acc[6] = fmaf(p, vb4.z, acc[6]);
            acc[7] = fmaf(p, vb4.w, acc[7]);
        }
    }

    // write unnormalized partials
    float4 o0, o1;
    o0.x = acc[0]; o0.y = acc[1]; o0.z = acc[2]; o0.w = acc[3];
    o1.x = acc[4]; o1.y = acc[5]; o1.z = acc[6]; o1.w = acc[7];
    *(float4*)(pe + sub * 8)     = o0;
    *(float4*)(pe + sub * 8 + 4) = o1;
    if (sub == 0) { pe[32] = m; pe[33] = l; }
}

// ---------------------------------------------------------------------------
// Merge split-K partials: out = sum_s w_s*acc_s / sum_s w_s*l_s,
// w_s = 2^(m_s - M). One thread per (row, 8-dim group).
// ---------------------------------------------------------------------------
__global__ __launch_bounds__(256) void merge_kernel(
    const float* __restrict__ part,
    float* __restrict__ out)
{
    const int gid = blockIdx.x * 256 + threadIdx.x;   // B*T*4 threads
    const int row = gid >> 2;
    const int sub = gid & 3;
    const int b   = row / T_SEQ;
    const int tr  = row - b * T_SEQ;
    const int rb  = tr / ROWS;
    const int r   = tr - rb * ROWS;

    const float* pe = part + ((long)(b * BPB + rb) * SEGS) * (16 * 36) + r * 36;

    float M = -1e30f;
    #pragma unroll
    for (int s = 0; s < SEGS; ++s) M = fmaxf(M, pe[s * 16 * 36 + 32]);

    float L = 0.f;
    float a[8];
    #pragma unroll
    for (int d = 0; d < 8; ++d) a[d] = 0.f;

    #pragma unroll
    for (int s = 0; s < SEGS; ++s) {
        const float* p = pe + s * 16 * 36;
        const float w = exp2f(p[32] - M);
        L = fmaf(w, p[33], L);
        const float4 a0 = *(const float4*)(p + sub * 8);
        const float4 a1 = *(const float4*)(p + sub * 8 + 4);
        a[0] = fmaf(w, a0.x, a[0]); a[1] = fmaf(w, a0.y, a[1]);
        a[2] = fmaf(w, a0.z, a[2]); a[3] = fmaf(w, a0.w, a[3]);
        a[4] = fmaf(w, a1.x, a[4]); a[5] = fmaf(w, a1.y, a[5]);
        a[6] = fmaf(w, a1.z, a[6]); a[7] = fmaf(w, a1.w, a[7]);
    }

    const float inv = 1.0f / L;
    float4 o0, o1;
    o0.x = a[0] * inv; o0.y = a[1] * inv; o0.z = a[2] * inv; o0.w = a[3] * inv;
    o1.x = a[4] * inv; o1.y = a[5] * inv; o1.z = a[6] * inv; o1.w = a[7] * inv;
    float* op = out + (long)row * HH + sub * 8;
    *(float4*)op       = o0;
    *(float4*)(op + 4) = o1;
}

// ---------------------------------------------------------------------------
extern "C" void kernel_launch(void* const* d_in, const int* in_sizes, int n_in,
                              void* d_out, int out_size, void* d_ws, size_t ws_size,
                              hipStream_t stream)
{
    const float* x  = (const float*)d_in[0];
    const float* Wk = (const float*)d_in[1];
    const float* Wq = (const float*)d_in[2];
    const float* Wv = (const float*)d_in[3];

    const int  B  = in_sizes[0] / (T_SEQ * CC);   // 4
    const long NT = (long)B * T_SEQ;              // 16384 rows

    float* qw   = (float*)d_ws;                   // [NT, 32] (log2-scaled q)
    float* kw   = qw + NT * HH;                   // [NT, 32]
    float* vw   = kw + NT * HH;                   // [NT, 32]
    float* part = vw + NT * HH;                   // [B*BPB*SEGS][16][36]
    float* out  = (float*)d_out;

    proj_kernel<<<dim3((int)(NT / 8)), dim3(256), 0, stream>>>(x, Wk, Wq, Wv, qw, kw, vw);

    attn_partial<<<dim3(B * BPB * SEGS), dim3(64), 0, stream>>>(qw, kw, vw, part);

    merge_kernel<<<dim3((int)(NT * 4 / 256)), dim3(256), 0, stream>>>(part, out);
}

// Round 3
// 342.153 us; speedup vs baseline: 1.4501x; 1.4501x over previous
//
#include <hip/hip_runtime.h>
#include <stdint.h>

#define T_SEQ 4096
#define CC    128
#define HH    32
#define ROWS  16               // query rows per attention wave
#define BK    16               // keys per LDS tile
#define BPB   (T_SEQ / ROWS)   // 256 row-blocks per batch

// ---------------------------------------------------------------------------
// async global->LDS, 16B per lane, linear dest (wave-uniform base + lane*16)
// ---------------------------------------------------------------------------
__device__ __forceinline__ void gll16(const float* g, float* l) {
    __builtin_amdgcn_global_load_lds(
        (const __attribute__((address_space(1))) uint32_t*)g,
        (__attribute__((address_space(3)))       uint32_t*)l,
        16, 0, 0);
}

// ---------------------------------------------------------------------------
// Projection: k,q,v = x @ W^T.  q pre-scaled by log2(e)/sqrt(H) so attention
// scores live in the log2 domain (exp2 = native v_exp_f32).
// ---------------------------------------------------------------------------
__global__ __launch_bounds__(256) void proj_kernel(
    const float* __restrict__ x,
    const float* __restrict__ Wk,
    const float* __restrict__ Wq,
    const float* __restrict__ Wv,
    float* __restrict__ qo,
    float* __restrict__ ko,
    float* __restrict__ vo)
{
    __shared__ __align__(16) float xs[8 * CC];
    const int t = threadIdx.x;
    const long rowBase = (long)blockIdx.x * 8;

    ((float4*)xs)[t] = ((const float4*)(x + rowBase * CC))[t];
    __syncthreads();

    const int r = t >> 5;
    const int h = t & 31;
    const float4* xr = (const float4*)(xs + r * CC);
    const float4* wk = (const float4*)(Wk + h * CC);
    const float4* wq = (const float4*)(Wq + h * CC);
    const float4* wv = (const float4*)(Wv + h * CC);

    float ak0 = 0.f, ak1 = 0.f, aq0 = 0.f, aq1 = 0.f, av0 = 0.f, av1 = 0.f;
    #pragma unroll
    for (int c = 0; c < CC / 4; c += 2) {
        const float4 x0 = xr[c];
        const float4 x1 = xr[c + 1];
        {
            const float4 a0 = wk[c], a1 = wk[c + 1];
            ak0 = fmaf(x0.x, a0.x, ak0); ak0 = fmaf(x0.y, a0.y, ak0);
            ak0 = fmaf(x0.z, a0.z, ak0); ak0 = fmaf(x0.w, a0.w, ak0);
            ak1 = fmaf(x1.x, a1.x, ak1); ak1 = fmaf(x1.y, a1.y, ak1);
            ak1 = fmaf(x1.z, a1.z, ak1); ak1 = fmaf(x1.w, a1.w, ak1);
        }
        {
            const float4 a0 = wq[c], a1 = wq[c + 1];
            aq0 = fmaf(x0.x, a0.x, aq0); aq0 = fmaf(x0.y, a0.y, aq0);
            aq0 = fmaf(x0.z, a0.z, aq0); aq0 = fmaf(x0.w, a0.w, aq0);
            aq1 = fmaf(x1.x, a1.x, aq1); aq1 = fmaf(x1.y, a1.y, aq1);
            aq1 = fmaf(x1.z, a1.z, aq1); aq1 = fmaf(x1.w, a1.w, aq1);
        }
        {
            const float4 a0 = wv[c], a1 = wv[c + 1];
            av0 = fmaf(x0.x, a0.x, av0); av0 = fmaf(x0.y, a0.y, av0);
            av0 = fmaf(x0.z, a0.z, av0); av0 = fmaf(x0.w, a0.w, av0);
            av1 = fmaf(x1.x, a1.x, av1); av1 = fmaf(x1.y, a1.y, av1);
            av1 = fmaf(x1.z, a1.z, av1); av1 = fmaf(x1.w, a1.w, av1);
        }
    }

    const long row = rowBase + r;
    const float qscale = 0.17677669529663687f * 1.4426950408889634f; // 1/sqrt(32)*log2(e)
    ko[row * HH + h] = ak0 + ak1;
    qo[row * HH + h] = (aq0 + aq1) * qscale;
    vo[row * HH + h] = av0 + av1;
}

// ---------------------------------------------------------------------------
// Split-K flash attention partial, SINGLE PASS (deferred tile-end rescale:
// p = exp2(s - m_old) immediately; rescale acc/l once per tile). No s[] array
// -> no scratch spill. K/V double-buffered in LDS via global_load_lds with
// counted vmcnt (single-wave block: no barriers at all).
// Partial entry per (b,rb,seg): 16 rows x 36 floats
//   [0..31]=unnorm acc, [32]=m (log2 domain), [33]=l, [34..35]=pad.
// ---------------------------------------------------------------------------
__global__ __launch_bounds__(64, 4) void attn_partial(
    const float* __restrict__ q,
    const float* __restrict__ k,
    const float* __restrict__ v,
    float* __restrict__ part,
    int segs)
{
    __shared__ __align__(16) float ks[2][BK * HH];   // 2 x 2KB
    __shared__ __align__(16) float vs[2][BK * HH];   // 2 x 2KB

    const int tid = threadIdx.x;
    const int nb  = gridDim.x / segs;          // B * BPB
    const int seg = blockIdx.x / nb;
    const int rem = blockIdx.x - seg * nb;
    const int b   = rem >> 8;                  // / BPB (BPB=256)
    const int rbi = rem & (BPB - 1);
    const int rb  = BPB - 1 - rbi;             // heavy row-blocks first
    const int r0  = rb * ROWS;
    const int r   = tid >> 2;
    const int row = r0 + r;
    const int sub = tid & 3;

    const int nTiles = r0 / BK + 1;            // ceil((r0+ROWS)/BK), ROWS==BK
    const int t0 = seg * nTiles / segs;
    const int t1 = (seg + 1) * nTiles / segs;

    float* pe = part + ((long)(b * BPB + rb) * segs + seg) * (16 * 36) + r * 36;

    if (t0 >= t1) {                            // empty segment
        const float4 z = {0.f, 0.f, 0.f, 0.f};
        *(float4*)(pe + sub * 8)     = z;
        *(float4*)(pe + sub * 8 + 4) = z;
        if (sub == 0) { pe[32] = -1e30f; pe[33] = 0.f; }
        return;
    }

    const long batchOff = (long)b * T_SEQ * HH;
    const float* qp = q + batchOff + (long)row * HH + sub * 8;
    const float4 q0 = *(const float4*)qp;
    const float4 q1 = *(const float4*)(qp + 4);

    const float* kb = k + batchOff;
    const float* vb = v + batchOff;

    // prologue: stage tile t0 into buffer 0 (4 x global_load_lds, 16B/lane)
    {
        const float* kt0 = kb + (long)t0 * BK * HH;   // 512 floats
        const float* vt0 = vb + (long)t0 * BK * HH;
        gll16(kt0 + tid * 4,       &ks[0][0]);
        gll16(kt0 + 256 + tid * 4, &ks[0][256]);
        gll16(vt0 + tid * 4,       &vs[0][0]);
        gll16(vt0 + 256 + tid * 4, &vs[0][256]);
    }

    float m = 0.f, l = 0.f;                    // m is a reference point, not true max
    float acc[8];
    #pragma unroll
    for (int d = 0; d < 8; ++d) acc[d] = 0.f;

    for (int kt = t0; kt < t1; ++kt) {
        const int buf = (kt - t0) & 1;
        if (kt + 1 < t1) {
            // async-stage next tile; counted wait leaves the 4 new loads in flight
            const float* kn = kb + (long)(kt + 1) * BK * HH;
            const float* vn = vb + (long)(kt + 1) * BK * HH;
            gll16(kn + tid * 4,       &ks[buf ^ 1][0]);
            gll16(kn + 256 + tid * 4, &ks[buf ^ 1][256]);
            gll16(vn + tid * 4,       &vs[buf ^ 1][0]);
            gll16(vn + 256 + tid * 4, &vs[buf ^ 1][256]);
            asm volatile("s_waitcnt vmcnt(4)" ::: "memory");
        } else {
            asm volatile("s_waitcnt vmcnt(0)" ::: "memory");
        }

        const float* ksb = &ks[buf][0];
        const float* vsb = &vs[buf][0];
        const int rowRel = row - kt * BK;      // mask keys j > rowRel
        float tmax = -1e30f;

        #pragma unroll
        for (int j = 0; j < BK; ++j) {
            const float4 ka  = *(const float4*)(ksb + j * HH + sub * 8);
            const float4 ka1 = *(const float4*)(ksb + j * HH + sub * 8 + 4);
            float d0 = ka.x * q0.x;
            d0 = fmaf(ka.y, q0.y, d0); d0 = fmaf(ka.z, q0.z, d0); d0 = fmaf(ka.w, q0.w, d0);
            float d1 = ka1.x * q1.x;
            d1 = fmaf(ka1.y, q1.y, d1); d1 = fmaf(ka1.z, q1.z, d1); d1 = fmaf(ka1.w, q1.w, d1);
            float sj = d0 + d1;
            sj += __shfl_xor(sj, 1);
            sj += __shfl_xor(sj, 2);
            sj = (j > rowRel) ? -1e30f : sj;   // causal mask (exp2 -> 0)
            tmax = fmaxf(tmax, sj);
            const float p = __builtin_amdgcn_exp2f(sj - m);
            l += p;
            const float4 va  = *(const float4*)(vsb + j * HH + sub * 8);
            const float4 va1 = *(const float4*)(vsb + j * HH + sub * 8 + 4);
            acc[0] = fmaf(p, va.x,  acc[0]);
            acc[1] = fmaf(p, va.y,  acc[1]);
            acc[2] = fmaf(p, va.z,  acc[2]);
            acc[3] = fmaf(p, va.w,  acc[3]);
            acc[4] = fmaf(p, va1.x, acc[4]);
            acc[5] = fmaf(p, va1.y, acc[5]);
            acc[6] = fmaf(p, va1.z, acc[6]);
            acc[7] = fmaf(p, va1.w, acc[7]);
        }

        // deferred rescale, once per tile (corr==1 when tmax <= m)
        const float mn   = fmaxf(m, tmax);
        const float corr = __builtin_amdgcn_exp2f(m - mn);
        l *= corr;
        #pragma unroll
        for (int d = 0; d < 8; ++d) acc[d] *= corr;
        m = mn;
    }

    float4 o0, o1;
    o0.x = acc[0]; o0.y = acc[1]; o0.z = acc[2]; o0.w = acc[3];
    o1.x = acc[4]; o1.y = acc[5]; o1.z = acc[6]; o1.w = acc[7];
    *(float4*)(pe + sub * 8)     = o0;
    *(float4*)(pe + sub * 8 + 4) = o1;
    if (sub == 0) { pe[32] = m; pe[33] = l; }
}

// ---------------------------------------------------------------------------
// Merge split-K partials: out = sum_s w_s*acc_s / sum_s w_s*l_s, w_s=2^(m_s-M)
// ---------------------------------------------------------------------------
__global__ __launch_bounds__(256) void merge_kernel(
    const float* __restrict__ part,
    float* __restrict__ out,
    int segs)
{
    const int gid = blockIdx.x * 256 + threadIdx.x;   // B*T*4 threads
    const int row = gid >> 2;
    const int sub = gid & 3;
    const int b   = row / T_SEQ;
    const int tr  = row - b * T_SEQ;
    const int rb  = tr / ROWS;
    const int r   = tr - rb * ROWS;

    const float* pe = part + ((long)(b * BPB + rb) * segs) * (16 * 36) + r * 36;

    float M = -1e30f;
    for (int s = 0; s < segs; ++s) M = fmaxf(M, pe[s * 16 * 36 + 32]);

    float L = 0.f;
    float a[8];
    #pragma unroll
    for (int d = 0; d < 8; ++d) a[d] = 0.f;

    for (int s = 0; s < segs; ++s) {
        const float* p = pe + s * 16 * 36;
        const float w = __builtin_amdgcn_exp2f(p[32] - M);
        L = fmaf(w, p[33], L);
        const float4 a0 = *(const float4*)(p + sub * 8);
        const float4 a1 = *(const float4*)(p + sub * 8 + 4);
        a[0] = fmaf(w, a0.x, a[0]); a[1] = fmaf(w, a0.y, a[1]);
        a[2] = fmaf(w, a0.z, a[2]); a[3] = fmaf(w, a0.w, a[3]);
        a[4] = fmaf(w, a1.x, a[4]); a[5] = fmaf(w, a1.y, a[5]);
        a[6] = fmaf(w, a1.z, a[6]); a[7] = fmaf(w, a1.w, a[7]);
    }

    const float inv = 1.0f / L;
    float4 o0, o1;
    o0.x = a[0] * inv; o0.y = a[1] * inv; o0.z = a[2] * inv; o0.w = a[3] * inv;
    o1.x = a[4] * inv; o1.y = a[5] * inv; o1.z = a[6] * inv; o1.w = a[7] * inv;
    float* op = out + (long)row * HH + sub * 8;
    *(float4*)op       = o0;
    *(float4*)(op + 4) = o1;
}

// ---------------------------------------------------------------------------
extern "C" void kernel_launch(void* const* d_in, const int* in_sizes, int n_in,
                              void* d_out, int out_size, void* d_ws, size_t ws_size,
                              hipStream_t stream)
{
    const float* x  = (const float*)d_in[0];
    const float* Wk = (const float*)d_in[1];
    const float* Wq = (const float*)d_in[2];
    const float* Wv = (const float*)d_in[3];

    const int  B  = in_sizes[0] / (T_SEQ * CC);   // 4
    const long NT = (long)B * T_SEQ;              // 16384 rows

    float* qw   = (float*)d_ws;                   // [NT,32] log2-scaled q
    float* kw   = qw + NT * HH;
    float* vw   = kw + NT * HH;
    float* partbuf = vw + NT * HH;
    float* out  = (float*)d_out;

    // adaptive split: prefer 8 segments if workspace allows
    const size_t baseBytes = (size_t)3 * NT * HH * sizeof(float);
    int segs = 8;
    if (baseBytes + (size_t)B * BPB * segs * 16 * 36 * sizeof(float) > ws_size) segs = 4;

    proj_kernel<<<dim3((int)(NT / 8)), dim3(256), 0, stream>>>(x, Wk, Wq, Wv, qw, kw, vw);

    attn_partial<<<dim3(B * BPB * segs), dim3(64), 0, stream>>>(qw, kw, vw, partbuf, segs);

    merge_kernel<<<dim3((int)(NT * 4 / 256)), dim3(256), 0, stream>>>(partbuf, out, segs);
}

// Round 4
// 307.386 us; speedup vs baseline: 1.6141x; 1.1131x over previous
//
#include <hip/hip_runtime.h>
#include <stdint.h>

#define T_SEQ 4096
#define CC    128
#define HH    32
#define ROWS  64               // query rows per attention wave (2 per lane)
#define BK    16               // keys per LDS tile
#define BPB   (T_SEQ / ROWS)   // 64 row-blocks per batch

// ---------------------------------------------------------------------------
// async global->LDS, 16B per lane, linear dest (wave-uniform base + lane*16)
// ---------------------------------------------------------------------------
__device__ __forceinline__ void gll16(const float* g, float* l) {
    __builtin_amdgcn_global_load_lds(
        (const __attribute__((address_space(1))) uint32_t*)g,
        (__attribute__((address_space(3)))       uint32_t*)l,
        16, 0, 0);
}

// cross-sublane (lane^1) reduce on the VALU pipe: v_mov_b32_dpp quad_perm
// [1,0,3,2] + add. Keeps the LDS pipe free (no ds_swizzle).
__device__ __forceinline__ float xor1_sum(float x) {
    const int y = __builtin_amdgcn_mov_dpp(__float_as_int(x), 0xB1, 0xF, 0xF, true);
    return x + __int_as_float(y);
}

// ---------------------------------------------------------------------------
// Projection: k,q,v = x @ W^T.  q pre-scaled by log2(e)/sqrt(H) so attention
// scores live in the log2 domain (exp2 = native v_exp_f32).
// ---------------------------------------------------------------------------
__global__ __launch_bounds__(256) void proj_kernel(
    const float* __restrict__ x,
    const float* __restrict__ Wk,
    const float* __restrict__ Wq,
    const float* __restrict__ Wv,
    float* __restrict__ qo,
    float* __restrict__ ko,
    float* __restrict__ vo)
{
    __shared__ __align__(16) float xs[8 * CC];
    const int t = threadIdx.x;
    const long rowBase = (long)blockIdx.x * 8;

    ((float4*)xs)[t] = ((const float4*)(x + rowBase * CC))[t];
    __syncthreads();

    const int r = t >> 5;
    const int h = t & 31;
    const float4* xr = (const float4*)(xs + r * CC);
    const float4* wk = (const float4*)(Wk + h * CC);
    const float4* wq = (const float4*)(Wq + h * CC);
    const float4* wv = (const float4*)(Wv + h * CC);

    float ak0 = 0.f, ak1 = 0.f, aq0 = 0.f, aq1 = 0.f, av0 = 0.f, av1 = 0.f;
    #pragma unroll
    for (int c = 0; c < CC / 4; c += 2) {
        const float4 x0 = xr[c];
        const float4 x1 = xr[c + 1];
        {
            const float4 a0 = wk[c], a1 = wk[c + 1];
            ak0 = fmaf(x0.x, a0.x, ak0); ak0 = fmaf(x0.y, a0.y, ak0);
            ak0 = fmaf(x0.z, a0.z, ak0); ak0 = fmaf(x0.w, a0.w, ak0);
            ak1 = fmaf(x1.x, a1.x, ak1); ak1 = fmaf(x1.y, a1.y, ak1);
            ak1 = fmaf(x1.z, a1.z, ak1); ak1 = fmaf(x1.w, a1.w, ak1);
        }
        {
            const float4 a0 = wq[c], a1 = wq[c + 1];
            aq0 = fmaf(x0.x, a0.x, aq0); aq0 = fmaf(x0.y, a0.y, aq0);
            aq0 = fmaf(x0.z, a0.z, aq0); aq0 = fmaf(x0.w, a0.w, aq0);
            aq1 = fmaf(x1.x, a1.x, aq1); aq1 = fmaf(x1.y, a1.y, aq1);
            aq1 = fmaf(x1.z, a1.z, aq1); aq1 = fmaf(x1.w, a1.w, aq1);
        }
        {
            const float4 a0 = wv[c], a1 = wv[c + 1];
            av0 = fmaf(x0.x, a0.x, av0); av0 = fmaf(x0.y, a0.y, av0);
            av0 = fmaf(x0.z, a0.z, av0); av0 = fmaf(x0.w, a0.w, av0);
            av1 = fmaf(x1.x, a1.x, av1); av1 = fmaf(x1.y, a1.y, av1);
            av1 = fmaf(x1.z, a1.z, av1); av1 = fmaf(x1.w, a1.w, av1);
        }
    }

    const long row = rowBase + r;
    const float qscale = 0.17677669529663687f * 1.4426950408889634f; // 1/sqrt(32)*log2(e)
    ko[row * HH + h] = ak0 + ak1;
    qo[row * HH + h] = (aq0 + aq1) * qscale;
    vo[row * HH + h] = av0 + av1;
}

// ---------------------------------------------------------------------------
// One 16-key tile: dots + online softmax (deferred rescale) + PV, for the
// lane's two rows (A and B). 2 sublanes x 16 dims; DPP xor1 completes dots.
// ---------------------------------------------------------------------------
template<bool MASKED>
__device__ __forceinline__ void tile_pass(
    const float* __restrict__ ksb, const float* __restrict__ vsb,
    const int sub, const int relA, const int relB,
    const float4 qa0, const float4 qa1, const float4 qa2, const float4 qa3,
    const float4 qb0, const float4 qb1, const float4 qb2, const float4 qb3,
    float& mA, float& lA, float& mB, float& lB,
    float4& accA0, float4& accA1, float4& accA2, float4& accA3,
    float4& accB0, float4& accB1, float4& accB2, float4& accB3)
{
    float tmaxA = -1e30f, tmaxB = -1e30f;
    #pragma unroll
    for (int j = 0; j < BK; ++j) {
        const float* kr = ksb + j * HH + sub * 16;
        const float4 k0 = *(const float4*)kr;
        const float4 k1 = *(const float4*)(kr + 4);
        const float4 k2 = *(const float4*)(kr + 8);
        const float4 k3 = *(const float4*)(kr + 12);

        float dA0 = k0.x * qa0.x;
        dA0 = fmaf(k0.y, qa0.y, dA0); dA0 = fmaf(k0.z, qa0.z, dA0); dA0 = fmaf(k0.w, qa0.w, dA0);
        dA0 = fmaf(k1.x, qa1.x, dA0); dA0 = fmaf(k1.y, qa1.y, dA0);
        dA0 = fmaf(k1.z, qa1.z, dA0); dA0 = fmaf(k1.w, qa1.w, dA0);
        float dA1 = k2.x * qa2.x;
        dA1 = fmaf(k2.y, qa2.y, dA1); dA1 = fmaf(k2.z, qa2.z, dA1); dA1 = fmaf(k2.w, qa2.w, dA1);
        dA1 = fmaf(k3.x, qa3.x, dA1); dA1 = fmaf(k3.y, qa3.y, dA1);
        dA1 = fmaf(k3.z, qa3.z, dA1); dA1 = fmaf(k3.w, qa3.w, dA1);

        float dB0 = k0.x * qb0.x;
        dB0 = fmaf(k0.y, qb0.y, dB0); dB0 = fmaf(k0.z, qb0.z, dB0); dB0 = fmaf(k0.w, qb0.w, dB0);
        dB0 = fmaf(k1.x, qb1.x, dB0); dB0 = fmaf(k1.y, qb1.y, dB0);
        dB0 = fmaf(k1.z, qb1.z, dB0); dB0 = fmaf(k1.w, qb1.w, dB0);
        float dB1 = k2.x * qb2.x;
        dB1 = fmaf(k2.y, qb2.y, dB1); dB1 = fmaf(k2.z, qb2.z, dB1); dB1 = fmaf(k2.w, qb2.w, dB1);
        dB1 = fmaf(k3.x, qb3.x, dB1); dB1 = fmaf(k3.y, qb3.y, dB1);
        dB1 = fmaf(k3.z, qb3.z, dB1); dB1 = fmaf(k3.w, qb3.w, dB1);

        float sA = xor1_sum(dA0 + dA1);   // both sublanes now hold full dot
        float sB = xor1_sum(dB0 + dB1);
        if (MASKED) {
            sA = (j > relA) ? -1e30f : sA;
            sB = (j > relB) ? -1e30f : sB;
        }
        tmaxA = fmaxf(tmaxA, sA);
        tmaxB = fmaxf(tmaxB, sB);
        const float pA = __builtin_amdgcn_exp2f(sA - mA);
        const float pB = __builtin_amdgcn_exp2f(sB - mB);
        lA += pA;
        lB += pB;

        const float* vr = vsb + j * HH + sub * 16;
        const float4 v0 = *(const float4*)vr;
        const float4 v1 = *(const float4*)(vr + 4);
        const float4 v2 = *(const float4*)(vr + 8);
        const float4 v3 = *(const float4*)(vr + 12);
        accA0.x = fmaf(pA, v0.x, accA0.x); accA0.y = fmaf(pA, v0.y, accA0.y);
        accA0.z = fmaf(pA, v0.z, accA0.z); accA0.w = fmaf(pA, v0.w, accA0.w);
        accA1.x = fmaf(pA, v1.x, accA1.x); accA1.y = fmaf(pA, v1.y, accA1.y);
        accA1.z = fmaf(pA, v1.z, accA1.z); accA1.w = fmaf(pA, v1.w, accA1.w);
        accA2.x = fmaf(pA, v2.x, accA2.x); accA2.y = fmaf(pA, v2.y, accA2.y);
        accA2.z = fmaf(pA, v2.z, accA2.z); accA2.w = fmaf(pA, v2.w, accA2.w);
        accA3.x = fmaf(pA, v3.x, accA3.x); accA3.y = fmaf(pA, v3.y, accA3.y);
        accA3.z = fmaf(pA, v3.z, accA3.z); accA3.w = fmaf(pA, v3.w, accA3.w);
        accB0.x = fmaf(pB, v0.x, accB0.x); accB0.y = fmaf(pB, v0.y, accB0.y);
        accB0.z = fmaf(pB, v0.z, accB0.z); accB0.w = fmaf(pB, v0.w, accB0.w);
        accB1.x = fmaf(pB, v1.x, accB1.x); accB1.y = fmaf(pB, v1.y, accB1.y);
        accB1.z = fmaf(pB, v1.z, accB1.z); accB1.w = fmaf(pB, v1.w, accB1.w);
        accB2.x = fmaf(pB, v2.x, accB2.x); accB2.y = fmaf(pB, v2.y, accB2.y);
        accB2.z = fmaf(pB, v2.z, accB2.z); accB2.w = fmaf(pB, v2.w, accB2.w);
        accB3.x = fmaf(pB, v3.x, accB3.x); accB3.y = fmaf(pB, v3.y, accB3.y);
        accB3.z = fmaf(pB, v3.z, accB3.z); accB3.w = fmaf(pB, v3.w, accB3.w);
    }

    // deferred per-tile rescale (corr==1 when tile max didn't grow)
    const float mnA = fmaxf(mA, tmaxA);
    const float cA  = __builtin_amdgcn_exp2f(mA - mnA);
    lA *= cA;
    accA0.x *= cA; accA0.y *= cA; accA0.z *= cA; accA0.w *= cA;
    accA1.x *= cA; accA1.y *= cA; accA1.z *= cA; accA1.w *= cA;
    accA2.x *= cA; accA2.y *= cA; accA2.z *= cA; accA2.w *= cA;
    accA3.x *= cA; accA3.y *= cA; accA3.z *= cA; accA3.w *= cA;
    mA = mnA;
    const float mnB = fmaxf(mB, tmaxB);
    const float cB  = __builtin_amdgcn_exp2f(mB - mnB);
    lB *= cB;
    accB0.x *= cB; accB0.y *= cB; accB0.z *= cB; accB0.w *= cB;
    accB1.x *= cB; accB1.y *= cB; accB1.z *= cB; accB1.w *= cB;
    accB2.x *= cB; accB2.y *= cB; accB2.z *= cB; accB2.w *= cB;
    accB3.x *= cB; accB3.y *= cB; accB3.z *= cB; accB3.w *= cB;
    mB = mnB;
}

// ---------------------------------------------------------------------------
// Split-K flash attention partial. One wave per block, 64 rows per wave:
// 32 row-groups x 2 sublanes (16 dims each), 2 rows per lane (A: r0+g,
// B: r0+32+g) so each K/V LDS read is reused for two rows.
// Partial entry per (b,rb,seg): 64 rows x 36 floats
//   [0..31]=unnorm acc, [32]=m (log2 domain), [33]=l, [34..35]=pad.
// ---------------------------------------------------------------------------
__global__ __launch_bounds__(64, 3) void attn_partial(
    const float* __restrict__ q,
    const float* __restrict__ k,
    const float* __restrict__ v,
    float* __restrict__ part,
    int segs)
{
    __shared__ __align__(16) float ks[2][BK * HH];   // 2 x 2KB
    __shared__ __align__(16) float vs[2][BK * HH];   // 2 x 2KB

    const int tid = threadIdx.x;
    const int nb  = gridDim.x / segs;          // B * BPB
    const int seg = blockIdx.x / nb;
    const int rem = blockIdx.x - seg * nb;
    const int b   = rem >> 6;                  // / BPB (BPB=64)
    const int rbi = rem & (BPB - 1);
    const int rb  = BPB - 1 - rbi;             // heavy row-blocks first
    const int r0  = rb * ROWS;
    const int g   = tid >> 1;
    const int sub = tid & 1;
    const int rowA = r0 + g;
    const int rowB = rowA + 32;

    const int nTiles = (r0 + ROWS) / BK;       // 4*rb + 4
    const int t0 = seg * nTiles / segs;
    const int t1 = (seg + 1) * nTiles / segs;

    float* pe  = part + ((long)(b * BPB + rb) * segs + seg) * (ROWS * 36);
    float* peA = pe + g * 36 + sub * 16;
    float* peB = pe + (32 + g) * 36 + sub * 16;

    if (t0 >= t1) {                            // empty segment
        const float4 z = {0.f, 0.f, 0.f, 0.f};
        ((float4*)peA)[0] = z; ((float4*)peA)[1] = z;
        ((float4*)peA)[2] = z; ((float4*)peA)[3] = z;
        ((float4*)peB)[0] = z; ((float4*)peB)[1] = z;
        ((float4*)peB)[2] = z; ((float4*)peB)[3] = z;
        if (sub == 0) {
            pe[g * 36 + 32]        = -1e30f; pe[g * 36 + 33]        = 0.f;
            pe[(32 + g) * 36 + 32] = -1e30f; pe[(32 + g) * 36 + 33] = 0.f;
        }
        return;
    }

    const long batchOff = (long)b * T_SEQ * HH;
    const float* qpA = q + batchOff + (long)rowA * HH + sub * 16;
    const float* qpB = q + batchOff + (long)rowB * HH + sub * 16;
    const float4 qa0 = ((const float4*)qpA)[0], qa1 = ((const float4*)qpA)[1],
                 qa2 = ((const float4*)qpA)[2], qa3 = ((const float4*)qpA)[3];
    const float4 qb0 = ((const float4*)qpB)[0], qb1 = ((const float4*)qpB)[1],
                 qb2 = ((const float4*)qpB)[2], qb3 = ((const float4*)qpB)[3];

    const float* kb = k + batchOff;
    const float* vb = v + batchOff;

    // prologue: stage tile t0 into buffer 0 (4 x global_load_lds, 16B/lane)
    {
        const float* kt0 = kb + (long)t0 * BK * HH;   // 512 floats
        const float* vt0 = vb + (long)t0 * BK * HH;
        gll16(kt0 + tid * 4,       &ks[0][0]);
        gll16(kt0 + 256 + tid * 4, &ks[0][256]);
        gll16(vt0 + tid * 4,       &vs[0][0]);
        gll16(vt0 + 256 + tid * 4, &vs[0][256]);
    }

    float mA = 0.f, lA = 0.f, mB = 0.f, lB = 0.f;   // m = reference point
    float4 accA0 = {0,0,0,0}, accA1 = {0,0,0,0}, accA2 = {0,0,0,0}, accA3 = {0,0,0,0};
    float4 accB0 = {0,0,0,0}, accB1 = {0,0,0,0}, accB2 = {0,0,0,0}, accB3 = {0,0,0,0};

    for (int kt = t0; kt < t1; ++kt) {
        const int buf = (kt - t0) & 1;
        if (kt + 1 < t1) {
            // async-stage next tile; counted wait keeps 4 new loads in flight
            const float* kn = kb + (long)(kt + 1) * BK * HH;
            const float* vn = vb + (long)(kt + 1) * BK * HH;
            gll16(kn + tid * 4,       &ks[buf ^ 1][0]);
            gll16(kn + 256 + tid * 4, &ks[buf ^ 1][256]);
            gll16(vn + tid * 4,       &vs[buf ^ 1][0]);
            gll16(vn + 256 + tid * 4, &vs[buf ^ 1][256]);
            asm volatile("s_waitcnt vmcnt(4)" ::: "memory");
        } else {
            asm volatile("s_waitcnt vmcnt(0)" ::: "memory");
        }

        const float* ksb = &ks[buf][0];
        const float* vsb = &vs[buf][0];
        const bool full = (kt * BK + BK - 1) <= r0;   // wave-uniform
        if (full) {
            tile_pass<false>(ksb, vsb, sub, 0, 0,
                             qa0, qa1, qa2, qa3, qb0, qb1, qb2, qb3,
                             mA, lA, mB, lB,
                             accA0, accA1, accA2, accA3,
                             accB0, accB1, accB2, accB3);
        } else {
            const int relA = rowA - kt * BK;
            const int relB = rowB - kt * BK;
            tile_pass<true>(ksb, vsb, sub, relA, relB,
                            qa0, qa1, qa2, qa3, qb0, qb1, qb2, qb3,
                            mA, lA, mB, lB,
                            accA0, accA1, accA2, accA3,
                            accB0, accB1, accB2, accB3);
        }
    }

    ((float4*)peA)[0] = accA0; ((float4*)peA)[1] = accA1;
    ((float4*)peA)[2] = accA2; ((float4*)peA)[3] = accA3;
    ((float4*)peB)[0] = accB0; ((float4*)peB)[1] = accB1;
    ((float4*)peB)[2] = accB2; ((float4*)peB)[3] = accB3;
    if (sub == 0) {
        pe[g * 36 + 32]        = mA; pe[g * 36 + 33]        = lA;
        pe[(32 + g) * 36 + 32] = mB; pe[(32 + g) * 36 + 33] = lB;
    }
}

// ---------------------------------------------------------------------------
// Merge split-K partials: out = sum_s w_s*acc_s / sum_s w_s*l_s, w_s=2^(m_s-M)
// ---------------------------------------------------------------------------
__global__ __launch_bounds__(256) void merge_kernel(
    const float* __restrict__ part,
    float* __restrict__ out,
    int segs)
{
    const int gid = blockIdx.x * 256 + threadIdx.x;   // B*T*4 threads
    const int row = gid >> 2;
    const int sub = gid & 3;
    const int b   = row / T_SEQ;
    const int tr  = row - b * T_SEQ;
    const int rb  = tr >> 6;                   // / ROWS
    const int r   = tr & (ROWS - 1);

    const float* pe = part + ((long)(b * BPB + rb) * segs) * (ROWS * 36) + r * 36;
    const long stride = ROWS * 36;

    float M = -1e30f;
    for (int s = 0; s < segs; ++s) M = fmaxf(M, pe[s * stride + 32]);

    float L = 0.f;
    float a[8];
    #pragma unroll
    for (int d = 0; d < 8; ++d) a[d] = 0.f;

    for (int s = 0; s < segs; ++s) {
        const float* p = pe + s * stride;
        const float w = __builtin_amdgcn_exp2f(p[32] - M);
        L = fmaf(w, p[33], L);
        const float4 a0 = *(const float4*)(p + sub * 8);
        const float4 a1 = *(const float4*)(p + sub * 8 + 4);
        a[0] = fmaf(w, a0.x, a[0]); a[1] = fmaf(w, a0.y, a[1]);
        a[2] = fmaf(w, a0.z, a[2]); a[3] = fmaf(w, a0.w, a[3]);
        a[4] = fmaf(w, a1.x, a[4]); a[5] = fmaf(w, a1.y, a[5]);
        a[6] = fmaf(w, a1.z, a[6]); a[7] = fmaf(w, a1.w, a[7]);
    }

    const float inv = 1.0f / L;
    float4 o0, o1;
    o0.x = a[0] * inv; o0.y = a[1] * inv; o0.z = a[2] * inv; o0.w = a[3] * inv;
    o1.x = a[4] * inv; o1.y = a[5] * inv; o1.z = a[6] * inv; o1.w = a[7] * inv;
    float* op = out + (long)row * HH + sub * 8;
    *(float4*)op       = o0;
    *(float4*)(op + 4) = o1;
}

// ---------------------------------------------------------------------------
extern "C" void kernel_launch(void* const* d_in, const int* in_sizes, int n_in,
                              void* d_out, int out_size, void* d_ws, size_t ws_size,
                              hipStream_t stream)
{
    const float* x  = (const float*)d_in[0];
    const float* Wk = (const float*)d_in[1];
    const float* Wq = (const float*)d_in[2];
    const float* Wv = (const float*)d_in[3];

    const int  B  = in_sizes[0] / (T_SEQ * CC);   // 4
    const long NT = (long)B * T_SEQ;              // 16384 rows

    float* qw   = (float*)d_ws;                   // [NT,32] log2-scaled q
    float* kw   = qw + NT * HH;
    float* vw   = kw + NT * HH;
    float* partbuf = vw + NT * HH;
    float* out  = (float*)d_out;

    // adaptive split: prefer 16 segments (occupancy) if workspace allows
    const size_t baseBytes = (size_t)3 * NT * HH * sizeof(float);
    int segs = 16;
    while (segs > 4 &&
           baseBytes + (size_t)B * BPB * segs * ROWS * 36 * sizeof(float) > ws_size)
        segs >>= 1;

    proj_kernel<<<dim3((int)(NT / 8)), dim3(256), 0, stream>>>(x, Wk, Wq, Wv, qw, kw, vw);

    attn_partial<<<dim3(B * BPB * segs), dim3(64), 0, stream>>>(qw, kw, vw, partbuf, segs);

    merge_kernel<<<dim3((int)(NT * 4 / 256)), dim3(256), 0, stream>>>(partbuf, out, segs);
}

// Round 8
// 207.068 us; speedup vs baseline: 2.3961x; 1.4845x over previous
//
#include <hip/hip_runtime.h>
#include <stdint.h>

#define T_SEQ 4096
#define CC    128
#define HH    32
#define QB    16               // query rows per wave
#define KC    32               // keys per chunk
#define BPB   (T_SEQ / QB)     // 256 row-blocks per batch
#define PST   36               // floats per row in a partial entry

typedef __attribute__((ext_vector_type(8))) short short8v;   // 8 bf16
typedef __attribute__((ext_vector_type(4))) float f32x4;

__device__ __forceinline__ unsigned short b16r(float x) {   // RNE fp32->bf16
    unsigned int u = __float_as_uint(x);
    return (unsigned short)((u + 0x7FFFu + ((u >> 16) & 1u)) >> 16);
}
__device__ __forceinline__ float b16f(unsigned short h) {
    return __uint_as_float(((unsigned int)h) << 16);
}
__device__ __forceinline__ unsigned int pk_bf16(float lo, float hi) {
    unsigned int r;
    asm("v_cvt_pk_bf16_f32 %0, %1, %2" : "=v"(r) : "v"(lo), "v"(hi));
    return r;   // low16 = bf16(lo), high16 = bf16(hi)
}

// ---------------------------------------------------------------------------
// Projection: k,q,v = x @ W^T -> split bf16 hi/lo. q pre-scaled by
// log2(e)/sqrt(32). V stored transposed per 32-key tile: vt[b][t][dim][key].
// ---------------------------------------------------------------------------
__global__ __launch_bounds__(256) void proj_kernel(
    const float* __restrict__ x,
    const float* __restrict__ Wk,
    const float* __restrict__ Wq,
    const float* __restrict__ Wv,
    unsigned short* __restrict__ qhp, unsigned short* __restrict__ qlp,
    unsigned short* __restrict__ khp, unsigned short* __restrict__ klp,
    unsigned short* __restrict__ vth, unsigned short* __restrict__ vtl)
{
    __shared__ __align__(16) float xs[8 * CC];
    const int t = threadIdx.x;
    const long rowBase = (long)blockIdx.x * 8;

    ((float4*)xs)[t] = ((const float4*)(x + rowBase * CC))[t];
    __syncthreads();

    const int r = t >> 5;
    const int h = t & 31;
    const float4* xr = (const float4*)(xs + r * CC);
    const float4* wk = (const float4*)(Wk + h * CC);
    const float4* wq = (const float4*)(Wq + h * CC);
    const float4* wv = (const float4*)(Wv + h * CC);

    float ak0 = 0.f, ak1 = 0.f, aq0 = 0.f, aq1 = 0.f, av0 = 0.f, av1 = 0.f;
    #pragma unroll
    for (int c = 0; c < CC / 4; c += 2) {
        const float4 x0 = xr[c];
        const float4 x1 = xr[c + 1];
        {
            const float4 a0 = wk[c], a1 = wk[c + 1];
            ak0 = fmaf(x0.x, a0.x, ak0); ak0 = fmaf(x0.y, a0.y, ak0);
            ak0 = fmaf(x0.z, a0.z, ak0); ak0 = fmaf(x0.w, a0.w, ak0);
            ak1 = fmaf(x1.x, a1.x, ak1); ak1 = fmaf(x1.y, a1.y, ak1);
            ak1 = fmaf(x1.z, a1.z, ak1); ak1 = fmaf(x1.w, a1.w, ak1);
        }
        {
            const float4 a0 = wq[c], a1 = wq[c + 1];
            aq0 = fmaf(x0.x, a0.x, aq0); aq0 = fmaf(x0.y, a0.y, aq0);
            aq0 = fmaf(x0.z, a0.z, aq0); aq0 = fmaf(x0.w, a0.w, aq0);
            aq1 = fmaf(x1.x, a1.x, aq1); aq1 = fmaf(x1.y, a1.y, aq1);
            aq1 = fmaf(x1.z, a1.z, aq1); aq1 = fmaf(x1.w, a1.w, aq1);
        }
        {
            const float4 a0 = wv[c], a1 = wv[c + 1];
            av0 = fmaf(x0.x, a0.x, av0); av0 = fmaf(x0.y, a0.y, av0);
            av0 = fmaf(x0.z, a0.z, av0); av0 = fmaf(x0.w, a0.w, av0);
            av1 = fmaf(x1.x, a1.x, av1); av1 = fmaf(x1.y, a1.y, av1);
            av1 = fmaf(x1.z, a1.z, av1); av1 = fmaf(x1.w, a1.w, av1);
        }
    }

    const long row = rowBase + r;
    const float qscale = 0.17677669529663687f * 1.4426950408889634f;
    const float kv = ak0 + ak1;
    const float qv = (aq0 + aq1) * qscale;
    const float vv = av0 + av1;

    const unsigned short khi = b16r(kv);
    khp[row * HH + h] = khi;
    klp[row * HH + h] = b16r(kv - b16f(khi));
    const unsigned short qhi = b16r(qv);
    qhp[row * HH + h] = qhi;
    qlp[row * HH + h] = b16r(qv - b16f(qhi));
    const unsigned short vhi = b16r(vv);
    const int bb = (int)(row >> 12);          // /T_SEQ
    const int tt = ((int)row >> 5) & 127;     // key-tile
    const int kk = (int)row & 31;             // key-in-tile
    const long vtix = (((long)(bb * 128 + tt) * 32) + h) * 32 + kk;
    vth[vtix] = vhi;
    vtl[vtix] = b16r(vv - b16f(vhi));
}

// ---------------------------------------------------------------------------
// MFMA flash attention partial. 1 wave/block, 16 Q-rows, 32 keys/chunk.
// Swapped QK^T: S^T-tile = mfma(K_frag, Q_frag); D: col=lane&15 (Q-row),
// key=(lane>>4)*4+reg [verified layout]. Split-precision bf16x3 everywhere.
// No LDS staging; K/V/Q bf16 arrays are L2-resident.
// Partial entry per (b,rb,seg): 16 rows x 36 floats:
//   [0..31]=unnorm O, [32]=m (log2 ref), [33]=l.
// ---------------------------------------------------------------------------
__global__ __launch_bounds__(64, 4) void attn_partial(
    const unsigned short* __restrict__ qhp, const unsigned short* __restrict__ qlp,
    const unsigned short* __restrict__ khp, const unsigned short* __restrict__ klp,
    const unsigned short* __restrict__ vth, const unsigned short* __restrict__ vtl,
    float* __restrict__ part, int segs)
{
    const int tid = threadIdx.x;
    const int r16 = tid & 15;
    const int g   = tid >> 4;
    const int g8  = g * 8;

    const int nb  = gridDim.x / segs;          // B * BPB
    const int seg = blockIdx.x / nb;
    const int rem = blockIdx.x - seg * nb;
    const int b   = rem >> 8;                  // / BPB
    const int rbi = rem & (BPB - 1);
    const int rb  = BPB - 1 - rbi;             // heavy row-blocks first
    const int qbase = rb * QB;
    const int qrow  = qbase + r16;             // batch-local

    const int nChunks = (qbase + QB + KC - 1) / KC;
    const int t0 = seg * nChunks / segs;
    const int t1 = (seg + 1) * nChunks / segs;

    float* pe = part + ((long)(b * BPB + rb) * segs + seg) * (QB * PST);

    if (t0 >= t1) {                            // empty segment
        #pragma unroll
        for (int rr = 0; rr < 4; ++rr) {
            pe[(4 * g + rr) * PST + r16]      = 0.f;
            pe[(4 * g + rr) * PST + 16 + r16] = 0.f;
        }
        if (tid < 16) { pe[r16 * PST + 32] = -1e30f; pe[r16 * PST + 33] = 0.f; }
        return;
    }

    // Q B-fragments (col = r16 = Q-row, k-dims g*8..+7), hoisted
    const long qoff = ((long)b * T_SEQ + qbase + r16) * HH + g8;
    const short8v qhf = *(const short8v*)(qhp + qoff);
    const short8v qlf = *(const short8v*)(qlp + qoff);

    const unsigned short* khb = khp + (long)b * T_SEQ * HH;
    const unsigned short* klb = klp + (long)b * T_SEQ * HH;
    const unsigned short* vthb = vth + (long)b * (T_SEQ / 32) * 1024;
    const unsigned short* vtlb = vtl + (long)b * (T_SEQ / 32) * 1024;

    float m = 0.f, lsum = 0.f;
    f32x4 o0 = {0.f, 0.f, 0.f, 0.f};
    f32x4 o1 = {0.f, 0.f, 0.f, 0.f};

    const int sA = r16 + ((g & 1) << 5);       // P-shuffle source lanes
    const int sB = sA + 16;
    const bool hiHalf = (g >= 2);
    const int g4 = g << 2;
    const float NEG = -1e30f;

    for (int c = t0; c < t1; ++c) {
        const int ck = c * KC;
        // K A-fragments (row = key = r16, k-dims g*8..+7), two 16-key tiles
        const unsigned short* krh = khb + (long)ck * HH + g8;
        const unsigned short* krl = klb + (long)ck * HH + g8;
        const short8v kh0 = *(const short8v*)(krh + (long)r16 * HH);
        const short8v kh1 = *(const short8v*)(krh + (long)(16 + r16) * HH);
        const short8v kl0 = *(const short8v*)(krl + (long)r16 * HH);
        const short8v kl1 = *(const short8v*)(krl + (long)(16 + r16) * HH);
        // V B-fragments (col = dim-in-half = r16, keys g*8..+7), two halves
        const unsigned short* vbh = vthb + (long)c * 1024 + (long)r16 * 32 + g8;
        const unsigned short* vbl = vtlb + (long)c * 1024 + (long)r16 * 32 + g8;
        const short8v vh0 = *(const short8v*)(vbh);
        const short8v vh1 = *(const short8v*)(vbh + 512);
        const short8v vl0 = *(const short8v*)(vbl);
        const short8v vl1 = *(const short8v*)(vbl + 512);

        // S^T tiles, bf16x3 split: Kh*Qh + Kh*Ql + Kl*Qh
        f32x4 s0 = {0.f, 0.f, 0.f, 0.f}, s1 = {0.f, 0.f, 0.f, 0.f};
        s0 = __builtin_amdgcn_mfma_f32_16x16x32_bf16(kh0, qhf, s0, 0, 0, 0);
        s0 = __builtin_amdgcn_mfma_f32_16x16x32_bf16(kh0, qlf, s0, 0, 0, 0);
        s0 = __builtin_amdgcn_mfma_f32_16x16x32_bf16(kl0, qhf, s0, 0, 0, 0);
        s1 = __builtin_amdgcn_mfma_f32_16x16x32_bf16(kh1, qhf, s1, 0, 0, 0);
        s1 = __builtin_amdgcn_mfma_f32_16x16x32_bf16(kh1, qlf, s1, 0, 0, 0);
        s1 = __builtin_amdgcn_mfma_f32_16x16x32_bf16(kl1, qhf, s1, 0, 0, 0);

        // causal mask: key (ck + 4g + reg [+16]) > qrow  ->  -inf
        const int kq0 = qrow - ck - 4 * g;
        const int kq1 = kq0 - 16;
        s0[0] = (0 > kq0) ? NEG : s0[0];
        s0[1] = (1 > kq0) ? NEG : s0[1];
        s0[2] = (2 > kq0) ? NEG : s0[2];
        s0[3] = (3 > kq0) ? NEG : s0[3];
        s1[0] = (0 > kq1) ? NEG : s1[0];
        s1[1] = (1 > kq1) ? NEG : s1[1];
        s1[2] = (2 > kq1) ? NEG : s1[2];
        s1[3] = (3 > kq1) ? NEG : s1[3];

        // tile max across the row's 4 lane-groups
        float tmax = fmaxf(fmaxf(fmaxf(s0[0], s0[1]), fmaxf(s0[2], s0[3])),
                           fmaxf(fmaxf(s1[0], s1[1]), fmaxf(s1[2], s1[3])));
        tmax = fmaxf(tmax, __shfl_xor(tmax, 16));
        tmax = fmaxf(tmax, __shfl_xor(tmax, 32));

        // p = exp2(s - m_old) (deferred rescale)
        const float p00 = __builtin_amdgcn_exp2f(s0[0] - m);
        const float p01 = __builtin_amdgcn_exp2f(s0[1] - m);
        const float p02 = __builtin_amdgcn_exp2f(s0[2] - m);
        const float p03 = __builtin_amdgcn_exp2f(s0[3] - m);
        const float p10 = __builtin_amdgcn_exp2f(s1[0] - m);
        const float p11 = __builtin_amdgcn_exp2f(s1[1] - m);
        const float p12 = __builtin_amdgcn_exp2f(s1[2] - m);
        const float p13 = __builtin_amdgcn_exp2f(s1[3] - m);
        float ps = ((p00 + p01) + (p02 + p03)) + ((p10 + p11) + (p12 + p13));
        ps += __shfl_xor(ps, 16);
        ps += __shfl_xor(ps, 32);

        // split P into bf16 hi/lo word pairs (word = 2 consecutive regs)
        const unsigned int h0a = pk_bf16(p00, p01), h0b = pk_bf16(p02, p03);
        const unsigned int h1a = pk_bf16(p10, p11), h1b = pk_bf16(p12, p13);
        const unsigned int l0a = pk_bf16(p00 - b16f((unsigned short)h0a),
                                         p01 - b16f((unsigned short)(h0a >> 16)));
        const unsigned int l0b = pk_bf16(p02 - b16f((unsigned short)h0b),
                                         p03 - b16f((unsigned short)(h0b >> 16)));
        const unsigned int l1a = pk_bf16(p10 - b16f((unsigned short)h1a),
                                         p11 - b16f((unsigned short)(h1a >> 16)));
        const unsigned int l1b = pk_bf16(p12 - b16f((unsigned short)h1b),
                                         p13 - b16f((unsigned short)(h1b >> 16)));

        // shuffle P words into PV A-fragment layout (keys 8g+2jw.. per word)
        unsigned int xa, xb;
        xa = __shfl(h0a, sA); xb = __shfl(h1a, sA);
        const unsigned int H0 = hiHalf ? xb : xa;
        xa = __shfl(h0b, sA); xb = __shfl(h1b, sA);
        const unsigned int H1 = hiHalf ? xb : xa;
        xa = __shfl(h0a, sB); xb = __shfl(h1a, sB);
        const unsigned int H2 = hiHalf ? xb : xa;
        xa = __shfl(h0b, sB); xb = __shfl(h1b, sB);
        const unsigned int H3 = hiHalf ? xb : xa;
        xa = __shfl(l0a, sA); xb = __shfl(l1a, sA);
        const unsigned int L0 = hiHalf ? xb : xa;
        xa = __shfl(l0b, sA); xb = __shfl(l1b, sA);
        const unsigned int L1 = hiHalf ? xb : xa;
        xa = __shfl(l0a, sB); xb = __shfl(l1a, sB);
        const unsigned int L2 = hiHalf ? xb : xa;
        xa = __shfl(l0b, sB); xb = __shfl(l1b, sB);
        const unsigned int L3 = hiHalf ? xb : xa;

        uint4 hw; hw.x = H0; hw.y = H1; hw.z = H2; hw.w = H3;
        uint4 lw; lw.x = L0; lw.y = L1; lw.z = L2; lw.w = L3;
        const short8v pH = __builtin_bit_cast(short8v, hw);
        const short8v pL = __builtin_bit_cast(short8v, lw);

        // PV, bf16x3 split: Ph*Vh + Ph*Vl + Pl*Vh (accumulate fp32)
        o0 = __builtin_amdgcn_mfma_f32_16x16x32_bf16(pH, vh0, o0, 0, 0, 0);
        o0 = __builtin_amdgcn_mfma_f32_16x16x32_bf16(pH, vl0, o0, 0, 0, 0);
        o0 = __builtin_amdgcn_mfma_f32_16x16x32_bf16(pL, vh0, o0, 0, 0, 0);
        o1 = __builtin_amdgcn_mfma_f32_16x16x32_bf16(pH, vh1, o1, 0, 0, 0);
        o1 = __builtin_amdgcn_mfma_f32_16x16x32_bf16(pH, vl1, o1, 0, 0, 0);
        o1 = __builtin_amdgcn_mfma_f32_16x16x32_bf16(pL, vh1, o1, 0, 0, 0);

        // deferred rescale (O-lane rows are 4g+r -> pull per-row corr)
        const float mn   = fmaxf(m, tmax);
        const float corr = __builtin_amdgcn_exp2f(m - mn);
        lsum = (lsum + ps) * corr;
        m = mn;
        const float c0 = __shfl(corr, g4);
        const float c1 = __shfl(corr, g4 + 1);
        const float c2 = __shfl(corr, g4 + 2);
        const float c3 = __shfl(corr, g4 + 3);
        o0[0] *= c0; o0[1] *= c1; o0[2] *= c2; o0[3] *= c3;
        o1[0] *= c0; o1[1] *= c1; o1[2] *= c2; o1[3] *= c3;
    }

    // write partials: O-lane holds rows 4g+r, dim halves r16 / 16+r16
    pe[(4 * g + 0) * PST + r16] = o0[0];
    pe[(4 * g + 1) * PST + r16] = o0[1];
    pe[(4 * g + 2) * PST + r16] = o0[2];
    pe[(4 * g + 3) * PST + r16] = o0[3];
    pe[(4 * g + 0) * PST + 16 + r16] = o1[0];
    pe[(4 * g + 1) * PST + 16 + r16] = o1[1];
    pe[(4 * g + 2) * PST + 16 + r16] = o1[2];
    pe[(4 * g + 3) * PST + 16 + r16] = o1[3];
    if (tid < 16) { pe[r16 * PST + 32] = m; pe[r16 * PST + 33] = lsum; }
}

// ---------------------------------------------------------------------------
// Merge split-K partials: out = sum_s w_s*acc_s / sum_s w_s*l_s, w_s=2^(m_s-M)
// ---------------------------------------------------------------------------
__global__ __launch_bounds__(256) void merge_kernel(
    const float* __restrict__ part,
    float* __restrict__ out,
    int segs)
{
    const int gid = blockIdx.x * 256 + threadIdx.x;   // B*T*4 threads
    const int row = gid >> 2;
    const int sub = gid & 3;
    const int b   = row / T_SEQ;
    const int tr  = row - b * T_SEQ;
    const int rb  = tr >> 4;                   // / QB
    const int r   = tr & (QB - 1);

    const float* pe = part + ((long)(b * BPB + rb) * segs) * (QB * PST) + r * PST;
    const long stride = QB * PST;

    float M = -1e30f;
    for (int s = 0; s < segs; ++s) M = fmaxf(M, pe[s * stride + 32]);

    float L = 0.f;
    float a[8];
    #pragma unroll
    for (int d = 0; d < 8; ++d) a[d] = 0.f;

    for (int s = 0; s < segs; ++s) {
        const float* p = pe + s * stride;
        const float w = __builtin_amdgcn_exp2f(p[32] - M);
        L = fmaf(w, p[33], L);
        const float4 a0 = *(const float4*)(p + sub * 8);
        const float4 a1 = *(const float4*)(p + sub * 8 + 4);
        a[0] = fmaf(w, a0.x, a[0]); a[1] = fmaf(w, a0.y, a[1]);
        a[2] = fmaf(w, a0.z, a[2]); a[3] = fmaf(w, a0.w, a[3]);
        a[4] = fmaf(w, a1.x, a[4]); a[5] = fmaf(w, a1.y, a[5]);
        a[6] = fmaf(w, a1.z, a[6]); a[7] = fmaf(w, a1.w, a[7]);
    }

    const float inv = 1.0f / L;
    float4 o0, o1;
    o0.x = a[0] * inv; o0.y = a[1] * inv; o0.z = a[2] * inv; o0.w = a[3] * inv;
    o1.x = a[4] * inv; o1.y = a[5] * inv; o1.z = a[6] * inv; o1.w = a[7] * inv;
    float* op = out + (long)row * HH + sub * 8;
    *(float4*)op       = o0;
    *(float4*)(op + 4) = o1;
}

// ---------------------------------------------------------------------------
extern "C" void kernel_launch(void* const* d_in, const int* in_sizes, int n_in,
                              void* d_out, int out_size, void* d_ws, size_t ws_size,
                              hipStream_t stream)
{
    const float* x  = (const float*)d_in[0];
    const float* Wk = (const float*)d_in[1];
    const float* Wq = (const float*)d_in[2];
    const float* Wv = (const float*)d_in[3];

    const int  B  = in_sizes[0] / (T_SEQ * CC);   // 4
    const long NT = (long)B * T_SEQ;              // 16384 rows

    unsigned short* qhp = (unsigned short*)d_ws;  // each array: NT*32 bf16
    unsigned short* qlp = qhp + NT * HH;
    unsigned short* khp = qlp + NT * HH;
    unsigned short* klp = khp + NT * HH;
    unsigned short* vth = klp + NT * HH;          // transposed tiles
    unsigned short* vtl = vth + NT * HH;
    float* partbuf = (float*)(vtl + NT * HH);
    float* out = (float*)d_out;

    const size_t baseBytes = (size_t)6 * NT * HH * sizeof(unsigned short);
    int segs = 8;
    while (segs > 1 &&
           baseBytes + (size_t)B * BPB * segs * QB * PST * sizeof(float) > ws_size)
        segs >>= 1;

    proj_kernel<<<dim3((int)(NT / 8)), dim3(256), 0, stream>>>(
        x, Wk, Wq, Wv, qhp, qlp, khp, klp, vth, vtl);

    attn_partial<<<dim3(B * BPB * segs), dim3(64), 0, stream>>>(
        qhp, qlp, khp, klp, vth, vtl, partbuf, segs);

    merge_kernel<<<dim3((int)(NT * 4 / 256)), dim3(256), 0, stream>>>(
        partbuf, out, segs);
}

// Round 10
// 127.570 us; speedup vs baseline: 3.8892x; 1.6232x over previous
//
#include <hip/hip_runtime.h>
#include <stdint.h>

#define T_SEQ 4096
#define CC    128
#define HH    32
#define QB    16               // query rows per attn wave
#define KC    32               // keys per chunk
#define BPB   (T_SEQ / QB)     // 256 row-blocks per batch
#define PST   36               // floats per row in a partial entry

typedef __attribute__((ext_vector_type(8))) short short8v;   // 8 bf16
typedef __attribute__((ext_vector_type(4))) float f32x4;

__device__ __forceinline__ unsigned short b16r(float x) {   // RNE fp32->bf16
    unsigned int u = __float_as_uint(x);
    return (unsigned short)((u + 0x7FFFu + ((u >> 16) & 1u)) >> 16);
}
__device__ __forceinline__ float b16f(unsigned short h) {
    return __uint_as_float(((unsigned int)h) << 16);
}
__device__ __forceinline__ unsigned int pk_bf16(float lo, float hi) {
    unsigned int r;
    asm("v_cvt_pk_bf16_f32 %0, %1, %2" : "=v"(r) : "v"(lo), "v"(hi));
    return r;   // low16 = bf16(lo), high16 = bf16(hi)
}

// ---------------------------------------------------------------------------
// Projection v2: k,q,v = x @ W^T -> split bf16 hi/lo.
// Round-8 profile: old proj was 95us, VALUBusy 8%, HBM 2% -> latency-bound on
// W loads (h=t&31 -> 32 distinct 512B-strided lines per wave load instr).
// Fix: W staged in LDS (padded rows, 4-way conflict = 1.58x only) + x tile in
// LDS (2-address broadcast reads = free). 32 rows/block, thread = (h, rq),
// 4 rows x 3 mats = 12 dots/thread. LDS 67KB -> 2 blocks/CU (legal on gfx950).
// ---------------------------------------------------------------------------
__global__ __launch_bounds__(256) void proj_kernel(
    const float* __restrict__ x,
    const float* __restrict__ Wk,
    const float* __restrict__ Wq,
    const float* __restrict__ Wv,
    unsigned short* __restrict__ qhp, unsigned short* __restrict__ qlp,
    unsigned short* __restrict__ khp, unsigned short* __restrict__ klp,
    unsigned short* __restrict__ vth, unsigned short* __restrict__ vtl)
{
    __shared__ __align__(16) float ws[3 * 32 * 132];   // W padded: 132 f/row
    __shared__ __align__(16) float xs[32 * CC];        // x tile (broadcast-read)

    const int t = threadIdx.x;
    const long rowBase = (long)blockIdx.x * 32;

    // stage W: 3072 float4, 12 per thread, coalesced; mat uniform per i
    #pragma unroll
    for (int i = 0; i < 12; ++i) {
        const int f4  = t + i * 256;          // 0..3071
        const int mat = f4 >> 10;             // uniform per i (256 | 1024)
        const int rem = f4 & 1023;            // float4 index within mat
        const int row = rem >> 5;
        const int col = rem & 31;
        const float* src = (mat == 0) ? Wk : ((mat == 1) ? Wq : Wv);
        const float4 w = ((const float4*)src)[rem];
        *(float4*)&ws[(mat * 32 + row) * 132 + col * 4] = w;
    }
    // stage x tile: 32 rows * 128 f = 1024 float4, 4 per thread, coalesced
    #pragma unroll
    for (int i = 0; i < 4; ++i) {
        ((float4*)xs)[t + i * 256] = ((const float4*)(x + rowBase * CC))[t + i * 256];
    }
    __syncthreads();

    const int h  = t & 31;
    const int rq = t >> 5;

    const float* wkr = &ws[(0 * 32 + h) * 132];
    const float* wqr = &ws[(1 * 32 + h) * 132];
    const float* wvr = &ws[(2 * 32 + h) * 132];
    const float* xr  = &xs[rq * CC];

    float ak[4] = {0.f, 0.f, 0.f, 0.f};
    float aq[4] = {0.f, 0.f, 0.f, 0.f};
    float av[4] = {0.f, 0.f, 0.f, 0.f};

    #pragma unroll 4
    for (int c = 0; c < 32; ++c) {
        const float4 wk4 = *(const float4*)(wkr + c * 4);
        const float4 wq4 = *(const float4*)(wqr + c * 4);
        const float4 wv4 = *(const float4*)(wvr + c * 4);
        #pragma unroll
        for (int i = 0; i < 4; ++i) {
            const float4 xv = *(const float4*)(xr + i * 8 * CC + c * 4);
            ak[i] = fmaf(xv.x, wk4.x, ak[i]); ak[i] = fmaf(xv.y, wk4.y, ak[i]);
            ak[i] = fmaf(xv.z, wk4.z, ak[i]); ak[i] = fmaf(xv.w, wk4.w, ak[i]);
            aq[i] = fmaf(xv.x, wq4.x, aq[i]); aq[i] = fmaf(xv.y, wq4.y, aq[i]);
            aq[i] = fmaf(xv.z, wq4.z, aq[i]); aq[i] = fmaf(xv.w, wq4.w, aq[i]);
            av[i] = fmaf(xv.x, wv4.x, av[i]); av[i] = fmaf(xv.y, wv4.y, av[i]);
            av[i] = fmaf(xv.z, wv4.z, av[i]); av[i] = fmaf(xv.w, wv4.w, av[i]);
        }
    }

    const float qscale = 0.17677669529663687f * 1.4426950408889634f; // 1/sqrt(32)*log2(e)
    #pragma unroll
    for (int i = 0; i < 4; ++i) {
        const long row = rowBase + rq + i * 8;
        const float kv = ak[i];
        const float qv = aq[i] * qscale;
        const float vv = av[i];

        const unsigned short khi = b16r(kv);
        khp[row * HH + h] = khi;
        klp[row * HH + h] = b16r(kv - b16f(khi));
        const unsigned short qhi = b16r(qv);
        qhp[row * HH + h] = qhi;
        qlp[row * HH + h] = b16r(qv - b16f(qhi));
        const unsigned short vhi = b16r(vv);
        const int bb = (int)(row >> 12);          // /T_SEQ
        const int tt = ((int)row >> 5) & 127;     // key-tile
        const int kk = (int)row & 31;             // key-in-tile
        const long vtix = (((long)(bb * 128 + tt) * 32) + h) * 32 + kk;
        vth[vtix] = vhi;
        vtl[vtix] = b16r(vv - b16f(vhi));
    }
}

// ---------------------------------------------------------------------------
// MFMA flash attention partial. 1 wave/block, 16 Q-rows, 32 keys/chunk.
// Swapped QK^T: S^T-tile = mfma(K_frag, Q_frag); D: col=lane&15 (Q-row),
// key=(lane>>4)*4+reg [verified layout]. Split-precision bf16x3 everywhere.
// No LDS staging; K/V/Q bf16 arrays are L2-resident.  (unchanged, r8-passed)
// ---------------------------------------------------------------------------
__global__ __launch_bounds__(64, 4) void attn_partial(
    const unsigned short* __restrict__ qhp, const unsigned short* __restrict__ qlp,
    const unsigned short* __restrict__ khp, const unsigned short* __restrict__ klp,
    const unsigned short* __restrict__ vth, const unsigned short* __restrict__ vtl,
    float* __restrict__ part, int segs)
{
    const int tid = threadIdx.x;
    const int r16 = tid & 15;
    const int g   = tid >> 4;
    const int g8  = g * 8;

    const int nb  = gridDim.x / segs;          // B * BPB
    const int seg = blockIdx.x / nb;
    const int rem = blockIdx.x - seg * nb;
    const int b   = rem >> 8;                  // / BPB
    const int rbi = rem & (BPB - 1);
    const int rb  = BPB - 1 - rbi;             // heavy row-blocks first
    const int qbase = rb * QB;
    const int qrow  = qbase + r16;             // batch-local

    const int nChunks = (qbase + QB + KC - 1) / KC;
    const int t0 = seg * nChunks / segs;
    const int t1 = (seg + 1) * nChunks / segs;

    float* pe = part + ((long)(b * BPB + rb) * segs + seg) * (QB * PST);

    if (t0 >= t1) {                            // empty segment
        #pragma unroll
        for (int rr = 0; rr < 4; ++rr) {
            pe[(4 * g + rr) * PST + r16]      = 0.f;
            pe[(4 * g + rr) * PST + 16 + r16] = 0.f;
        }
        if (tid < 16) { pe[r16 * PST + 32] = -1e30f; pe[r16 * PST + 33] = 0.f; }
        return;
    }

    // Q B-fragments (col = r16 = Q-row, k-dims g*8..+7), hoisted
    const long qoff = ((long)b * T_SEQ + qbase + r16) * HH + g8;
    const short8v qhf = *(const short8v*)(qhp + qoff);
    const short8v qlf = *(const short8v*)(qlp + qoff);

    const unsigned short* khb = khp + (long)b * T_SEQ * HH;
    const unsigned short* klb = klp + (long)b * T_SEQ * HH;
    const unsigned short* vthb = vth + (long)b * (T_SEQ / 32) * 1024;
    const unsigned short* vtlb = vtl + (long)b * (T_SEQ / 32) * 1024;

    float m = 0.f, lsum = 0.f;
    f32x4 o0 = {0.f, 0.f, 0.f, 0.f};
    f32x4 o1 = {0.f, 0.f, 0.f, 0.f};

    const int sA = r16 + ((g & 1) << 5);       // P-shuffle source lanes
    const int sB = sA + 16;
    const bool hiHalf = (g >= 2);
    const int g4 = g << 2;
    const float NEG = -1e30f;

    for (int c = t0; c < t1; ++c) {
        const int ck = c * KC;
        // K A-fragments (row = key = r16, k-dims g*8..+7), two 16-key tiles
        const unsigned short* krh = khb + (long)ck * HH + g8;
        const unsigned short* krl = klb + (long)ck * HH + g8;
        const short8v kh0 = *(const short8v*)(krh + (long)r16 * HH);
        const short8v kh1 = *(const short8v*)(krh + (long)(16 + r16) * HH);
        const short8v kl0 = *(const short8v*)(krl + (long)r16 * HH);
        const short8v kl1 = *(const short8v*)(krl + (long)(16 + r16) * HH);
        // V B-fragments (col = dim-in-half = r16, keys g*8..+7), two halves
        const unsigned short* vbh = vthb + (long)c * 1024 + (long)r16 * 32 + g8;
        const unsigned short* vbl = vtlb + (long)c * 1024 + (long)r16 * 32 + g8;
        const short8v vh0 = *(const short8v*)(vbh);
        const short8v vh1 = *(const short8v*)(vbh + 512);
        const short8v vl0 = *(const short8v*)(vbl);
        const short8v vl1 = *(const short8v*)(vbl + 512);

        // S^T tiles, bf16x3 split: Kh*Qh + Kh*Ql + Kl*Qh
        f32x4 s0 = {0.f, 0.f, 0.f, 0.f}, s1 = {0.f, 0.f, 0.f, 0.f};
        s0 = __builtin_amdgcn_mfma_f32_16x16x32_bf16(kh0, qhf, s0, 0, 0, 0);
        s0 = __builtin_amdgcn_mfma_f32_16x16x32_bf16(kh0, qlf, s0, 0, 0, 0);
        s0 = __builtin_amdgcn_mfma_f32_16x16x32_bf16(kl0, qhf, s0, 0, 0, 0);
        s1 = __builtin_amdgcn_mfma_f32_16x16x32_bf16(kh1, qhf, s1, 0, 0, 0);
        s1 = __builtin_amdgcn_mfma_f32_16x16x32_bf16(kh1, qlf, s1, 0, 0, 0);
        s1 = __builtin_amdgcn_mfma_f32_16x16x32_bf16(kl1, qhf, s1, 0, 0, 0);

        // causal mask: key (ck + 4g + reg [+16]) > qrow  ->  -inf
        const int kq0 = qrow - ck - 4 * g;
        const int kq1 = kq0 - 16;
        s0[0] = (0 > kq0) ? NEG : s0[0];
        s0[1] = (1 > kq0) ? NEG : s0[1];
        s0[2] = (2 > kq0) ? NEG : s0[2];
        s0[3] = (3 > kq0) ? NEG : s0[3];
        s1[0] = (0 > kq1) ? NEG : s1[0];
        s1[1] = (1 > kq1) ? NEG : s1[1];
        s1[2] = (2 > kq1) ? NEG : s1[2];
        s1[3] = (3 > kq1) ? NEG : s1[3];

        // tile max across the row's 4 lane-groups
        float tmax = fmaxf(fmaxf(fmaxf(s0[0], s0[1]), fmaxf(s0[2], s0[3])),
                           fmaxf(fmaxf(s1[0], s1[1]), fmaxf(s1[2], s1[3])));
        tmax = fmaxf(tmax, __shfl_xor(tmax, 16));
        tmax = fmaxf(tmax, __shfl_xor(tmax, 32));

        // p = exp2(s - m_old) (deferred rescale)
        const float p00 = __builtin_amdgcn_exp2f(s0[0] - m);
        const float p01 = __builtin_amdgcn_exp2f(s0[1] - m);
        const float p02 = __builtin_amdgcn_exp2f(s0[2] - m);
        const float p03 = __builtin_amdgcn_exp2f(s0[3] - m);
        const float p10 = __builtin_amdgcn_exp2f(s1[0] - m);
        const float p11 = __builtin_amdgcn_exp2f(s1[1] - m);
        const float p12 = __builtin_amdgcn_exp2f(s1[2] - m);
        const float p13 = __builtin_amdgcn_exp2f(s1[3] - m);
        float ps = ((p00 + p01) + (p02 + p03)) + ((p10 + p11) + (p12 + p13));
        ps += __shfl_xor(ps, 16);
        ps += __shfl_xor(ps, 32);

        // split P into bf16 hi/lo word pairs (word = 2 consecutive regs)
        const unsigned int h0a = pk_bf16(p00, p01), h0b = pk_bf16(p02, p03);
        const unsigned int h1a = pk_bf16(p10, p11), h1b = pk_bf16(p12, p13);
        const unsigned int l0a = pk_bf16(p00 - b16f((unsigned short)h0a),
                                         p01 - b16f((unsigned short)(h0a >> 16)));
        const unsigned int l0b = pk_bf16(p02 - b16f((unsigned short)h0b),
                                         p03 - b16f((unsigned short)(h0b >> 16)));
        const unsigned int l1a = pk_bf16(p10 - b16f((unsigned short)h1a),
                                         p11 - b16f((unsigned short)(h1a >> 16)));
        const unsigned int l1b = pk_bf16(p12 - b16f((unsigned short)h1b),
                                         p13 - b16f((unsigned short)(h1b >> 16)));

        // shuffle P words into PV A-fragment layout (keys 8g+2jw.. per word)
        unsigned int xa, xb;
        xa = __shfl(h0a, sA); xb = __shfl(h1a, sA);
        const unsigned int H0 = hiHalf ? xb : xa;
        xa = __shfl(h0b, sA); xb = __shfl(h1b, sA);
        const unsigned int H1 = hiHalf ? xb : xa;
        xa = __shfl(h0a, sB); xb = __shfl(h1a, sB);
        const unsigned int H2 = hiHalf ? xb : xa;
        xa = __shfl(h0b, sB); xb = __shfl(h1b, sB);
        const unsigned int H3 = hiHalf ? xb : xa;
        xa = __shfl(l0a, sA); xb = __shfl(l1a, sA);
        const unsigned int L0 = hiHalf ? xb : xa;
        xa = __shfl(l0b, sA); xb = __shfl(l1b, sA);
        const unsigned int L1 = hiHalf ? xb : xa;
        xa = __shfl(l0a, sB); xb = __shfl(l1a, sB);
        const unsigned int L2 = hiHalf ? xb : xa;
        xa = __shfl(l0b, sB); xb = __shfl(l1b, sB);
        const unsigned int L3 = hiHalf ? xb : xa;

        uint4 hw; hw.x = H0; hw.y = H1; hw.z = H2; hw.w = H3;
        uint4 lw; lw.x = L0; lw.y = L1; lw.z = L2; lw.w = L3;
        const short8v pH = __builtin_bit_cast(short8v, hw);
        const short8v pL = __builtin_bit_cast(short8v, lw);

        // PV, bf16x3 split: Ph*Vh + Ph*Vl + Pl*Vh (accumulate fp32)
        o0 = __builtin_amdgcn_mfma_f32_16x16x32_bf16(pH, vh0, o0, 0, 0, 0);
        o0 = __builtin_amdgcn_mfma_f32_16x16x32_bf16(pH, vl0, o0, 0, 0, 0);
        o0 = __builtin_amdgcn_mfma_f32_16x16x32_bf16(pL, vh0, o0, 0, 0, 0);
        o1 = __builtin_amdgcn_mfma_f32_16x16x32_bf16(pH, vh1, o1, 0, 0, 0);
        o1 = __builtin_amdgcn_mfma_f32_16x16x32_bf16(pH, vl1, o1, 0, 0, 0);
        o1 = __builtin_amdgcn_mfma_f32_16x16x32_bf16(pL, vh1, o1, 0, 0, 0);

        // deferred rescale (O-lane rows are 4g+r -> pull per-row corr)
        const float mn   = fmaxf(m, tmax);
        const float corr = __builtin_amdgcn_exp2f(m - mn);
        lsum = (lsum + ps) * corr;
        m = mn;
        const float c0 = __shfl(corr, g4);
        const float c1 = __shfl(corr, g4 + 1);
        const float c2 = __shfl(corr, g4 + 2);
        const float c3 = __shfl(corr, g4 + 3);
        o0[0] *= c0; o0[1] *= c1; o0[2] *= c2; o0[3] *= c3;
        o1[0] *= c0; o1[1] *= c1; o1[2] *= c2; o1[3] *= c3;
    }

    // write partials: O-lane holds rows 4g+r, dim halves r16 / 16+r16
    pe[(4 * g + 0) * PST + r16] = o0[0];
    pe[(4 * g + 1) * PST + r16] = o0[1];
    pe[(4 * g + 2) * PST + r16] = o0[2];
    pe[(4 * g + 3) * PST + r16] = o0[3];
    pe[(4 * g + 0) * PST + 16 + r16] = o1[0];
    pe[(4 * g + 1) * PST + 16 + r16] = o1[1];
    pe[(4 * g + 2) * PST + 16 + r16] = o1[2];
    pe[(4 * g + 3) * PST + 16 + r16] = o1[3];
    if (tid < 16) { pe[r16 * PST + 32] = m; pe[r16 * PST + 33] = lsum; }
}

// ---------------------------------------------------------------------------
// Merge split-K partials: out = sum_s w_s*acc_s / sum_s w_s*l_s, w_s=2^(m_s-M)
// ---------------------------------------------------------------------------
__global__ __launch_bounds__(256) void merge_kernel(
    const float* __restrict__ part,
    float* __restrict__ out,
    int segs)
{
    const int gid = blockIdx.x * 256 + threadIdx.x;   // B*T*4 threads
    const int row = gid >> 2;
    const int sub = gid & 3;
    const int b   = row / T_SEQ;
    const int tr  = row - b * T_SEQ;
    const int rb  = tr >> 4;                   // / QB
    const int r   = tr & (QB - 1);

    const float* pe = part + ((long)(b * BPB + rb) * segs) * (QB * PST) + r * PST;
    const long stride = QB * PST;

    float M = -1e30f;
    for (int s = 0; s < segs; ++s) M = fmaxf(M, pe[s * stride + 32]);

    float L = 0.f;
    float a[8];
    #pragma unroll
    for (int d = 0; d < 8; ++d) a[d] = 0.f;

    for (int s = 0; s < segs; ++s) {
        const float* p = pe + s * stride;
        const float w = __builtin_amdgcn_exp2f(p[32] - M);
        L = fmaf(w, p[33], L);
        const float4 a0 = *(const float4*)(p + sub * 8);
        const float4 a1 = *(const float4*)(p + sub * 8 + 4);
        a[0] = fmaf(w, a0.x, a[0]); a[1] = fmaf(w, a0.y, a[1]);
        a[2] = fmaf(w, a0.z, a[2]); a[3] = fmaf(w, a0.w, a[3]);
        a[4] = fmaf(w, a1.x, a[4]); a[5] = fmaf(w, a1.y, a[5]);
        a[6] = fmaf(w, a1.z, a[6]); a[7] = fmaf(w, a1.w, a[7]);
    }

    const float inv = 1.0f / L;
    float4 o0, o1;
    o0.x = a[0] * inv; o0.y = a[1] * inv; o0.z = a[2] * inv; o0.w = a[3] * inv;
    o1.x = a[4] * inv; o1.y = a[5] * inv; o1.z = a[6] * inv; o1.w = a[7] * inv;
    float* op = out + (long)row * HH + sub * 8;
    *(float4*)op       = o0;
    *(float4*)(op + 4) = o1;
}

// ---------------------------------------------------------------------------
extern "C" void kernel_launch(void* const* d_in, const int* in_sizes, int n_in,
                              void* d_out, int out_size, void* d_ws, size_t ws_size,
                              hipStream_t stream)
{
    const float* x  = (const float*)d_in[0];
    const float* Wk = (const float*)d_in[1];
    const float* Wq = (const float*)d_in[2];
    const float* Wv = (const float*)d_in[3];

    const int  B  = in_sizes[0] / (T_SEQ * CC);   // 4
    const long NT = (long)B * T_SEQ;              // 16384 rows

    unsigned short* qhp = (unsigned short*)d_ws;  // each array: NT*32 bf16
    unsigned short* qlp = qhp + NT * HH;
    unsigned short* khp = qlp + NT * HH;
    unsigned short* klp = khp + NT * HH;
    unsigned short* vth = klp + NT * HH;          // transposed tiles
    unsigned short* vtl = vth + NT * HH;
    float* partbuf = (float*)(vtl + NT * HH);
    float* out = (float*)d_out;

    const size_t baseBytes = (size_t)6 * NT * HH * sizeof(unsigned short);
    int segs = 8;
    while (segs > 1 &&
           baseBytes + (size_t)B * BPB * segs * QB * PST * sizeof(float) > ws_size)
        segs >>= 1;

    proj_kernel<<<dim3((int)(NT / 32)), dim3(256), 0, stream>>>(
        x, Wk, Wq, Wv, qhp, qlp, khp, klp, vth, vtl);

    attn_partial<<<dim3(B * BPB * segs), dim3(64), 0, stream>>>(
        qhp, qlp, khp, klp, vth, vtl, partbuf, segs);

    merge_kernel<<<dim3((int)(NT * 4 / 256)), dim3(256), 0, stream>>>(
        partbuf, out, segs);
}